// Round 1
// baseline (904.850 us; speedup 1.0000x reference)
//
#include <hip/hip_runtime.h>

#define NNODE 100000
#define NEDGE 1600000

// ---------------- K1: feat = h @ W_fc, plus el/er ----------------
__global__ __launch_bounds__(256) void k_proj(
        const float* __restrict__ hin, const float* __restrict__ Wfc,
        const float* __restrict__ attn_l, const float* __restrict__ attn_r,
        float* __restrict__ feat, float* __restrict__ el, float* __restrict__ er) {
    __shared__ float sW[32 * 128];   // 16 KB
    __shared__ float sh[64 * 32];    // 8 KB
    int tid = threadIdx.x;
    // stage W_fc (4096 floats), 16 per thread
    for (int i = tid * 4; i < 4096; i += 256 * 4)
        *(float4*)&sW[i] = *(const float4*)&Wfc[i];
    int nbase = blockIdx.x * 64;
    // stage h tile (64 nodes x 32), coalesced float4
    for (int i = tid * 4; i < 2048; i += 1024) {
        int n = nbase + (i >> 5);
        float4 v = make_float4(0.f, 0.f, 0.f, 0.f);
        if (n < NNODE) v = *(const float4*)&hin[n * 32 + (i & 31)];
        *(float4*)&sh[i] = v;
    }
    __syncthreads();
    int nl = tid >> 2, hh = tid & 3;
    int n = nbase + nl;
    float acc[32];
#pragma unroll
    for (int d = 0; d < 32; d++) acc[d] = 0.f;
#pragma unroll 8
    for (int k = 0; k < 32; k++) {
        float hk = sh[nl * 32 + k];
#pragma unroll
        for (int d = 0; d < 32; d++)
            acc[d] = fmaf(hk, sW[k * 128 + hh * 32 + d], acc[d]);
    }
    if (n < NNODE) {
        float e_l = 0.f, e_r = 0.f;
#pragma unroll
        for (int d = 0; d < 32; d++) {
            e_l = fmaf(acc[d], attn_l[hh * 32 + d], e_l);
            e_r = fmaf(acc[d], attn_r[hh * 32 + d], e_r);
        }
        el[n * 4 + hh] = e_l;
        er[n * 4 + hh] = e_r;
#pragma unroll
        for (int d = 0; d < 32; d += 4)
            *(float4*)&feat[n * 128 + hh * 32 + d] =
                make_float4(acc[d], acc[d + 1], acc[d + 2], acc[d + 3]);
    }
}

// ---------------- K2: edge pass — exp(leakyrelu(el[s]+er[d])), scatter ----------------
// 128 lanes per edge (c = column 0..127), 2 edges per 256-thread block slice,
// EPB edges per block total.
#define EPB 16
__global__ __launch_bounds__(256) void k_edge(
        const int* __restrict__ src, const int* __restrict__ dst,
        const float* __restrict__ el, const float* __restrict__ er,
        const float* __restrict__ feat,
        float* __restrict__ rst, float* __restrict__ denom) {
    int tid = threadIdx.x;
    int c  = tid & 127;
    int lp = tid >> 7;       // 0 or 1
    int hh = c >> 5;
    int ebase = blockIdx.x * EPB;
#pragma unroll
    for (int i = 0; i < EPB / 2; i++) {
        int e = ebase + i * 2 + lp;
        int s = src[e], d = dst[e];
        float sc = el[s * 4 + hh] + er[d * 4 + hh];
        sc = sc > 0.f ? sc : 0.2f * sc;
        float ex = __expf(sc);
        float fv = feat[s * 128 + c];
        atomicAdd(&rst[d * 128 + c], ex * fv);
        if ((c & 31) == 0) atomicAdd(&denom[d * 4 + hh], ex);
    }
}

// ---------------- K3: normalize, out-projection, ELU, residual ----------------
__global__ __launch_bounds__(256) void k_out(
        const float* __restrict__ rst, const float* __restrict__ denom,
        const float* __restrict__ bias_gat, const float* __restrict__ Wout,
        const float* __restrict__ b_out, const float* __restrict__ hin,
        float* __restrict__ out) {
    __shared__ float sW[128 * 32];   // 16 KB
    __shared__ float sv[8][128];
    int tid = threadIdx.x;
    for (int i = tid * 4; i < 4096; i += 1024)
        *(float4*)&sW[i] = *(const float4*)&Wout[i];
    int nl = tid >> 5, j = tid & 31;
    int n = blockIdx.x * 8 + nl;
    // load rst columns j, j+32, j+64, j+96 (coalesced per k), normalize
#pragma unroll
    for (int k = 0; k < 4; k++) {
        int cc = j + k * 32;
        float dn = denom[n * 4 + k];
        float val = rst[n * 128 + cc] / fmaxf(dn, 1e-9f) + bias_gat[cc];
        sv[nl][cc] = val;
    }
    __syncthreads();
    float acc = b_out[j];
    const float* vv = sv[nl];
#pragma unroll 16
    for (int cc = 0; cc < 128; cc++)
        acc = fmaf(vv[cc], sW[cc * 32 + j], acc);
    float r = hin[n * 32 + j];
    acc = acc > 0.f ? acc : expm1f(acc);
    out[n * 32 + j] = r + acc;
}

extern "C" void kernel_launch(void* const* d_in, const int* in_sizes, int n_in,
                              void* d_out, int out_size, void* d_ws, size_t ws_size,
                              hipStream_t stream) {
    const float* hin      = (const float*)d_in[0];
    const int*   src      = (const int*)d_in[1];
    const int*   dst      = (const int*)d_in[2];
    const float* Wfc      = (const float*)d_in[3];
    const float* attn_l   = (const float*)d_in[4];
    const float* attn_r   = (const float*)d_in[5];
    const float* bias_gat = (const float*)d_in[6];
    const float* Wout     = (const float*)d_in[7];
    const float* b_out    = (const float*)d_in[8];
    float* out = (float*)d_out;

    char* ws = (char*)d_ws;
    size_t off = 0;
    float* feat  = (float*)(ws + off); off += (size_t)NNODE * 128 * 4;
    float* el    = (float*)(ws + off); off += (size_t)NNODE * 4 * 4;
    float* er    = (float*)(ws + off); off += (size_t)NNODE * 4 * 4;
    float* denom = (float*)(ws + off); off += (size_t)NNODE * 4 * 4;
    float* rst   = (float*)(ws + off); off += (size_t)NNODE * 128 * 4;

    // zero denom + rst (contiguous) — accumulated via atomics
    hipMemsetAsync(denom, 0, (size_t)NNODE * 4 * 4 + (size_t)NNODE * 128 * 4, stream);

    k_proj<<<(NNODE + 63) / 64, 256, 0, stream>>>(hin, Wfc, attn_l, attn_r, feat, el, er);
    k_edge<<<NEDGE / EPB, 256, 0, stream>>>(src, dst, el, er, feat, rst, denom);
    k_out<<<NNODE / 8, 256, 0, stream>>>(rst, denom, bias_gat, Wout, b_out, hin, out);
}

// Round 2
// 602.671 us; speedup vs baseline: 1.5014x; 1.5014x over previous
//
#include <hip/hip_runtime.h>

#define NNODE 100000
#define NEDGE 1600000
#define NBLK_SCAN 98   // ceil(100000/1024)

// ---------------- K1: feat = h @ W_fc, plus el/er ----------------
__global__ __launch_bounds__(256) void k_proj(
        const float* __restrict__ hin, const float* __restrict__ Wfc,
        const float* __restrict__ attn_l, const float* __restrict__ attn_r,
        float* __restrict__ feat, float* __restrict__ el, float* __restrict__ er) {
    __shared__ float sW[32 * 128];   // 16 KB
    __shared__ float sh[64 * 32];    // 8 KB
    int tid = threadIdx.x;
    for (int i = tid * 4; i < 4096; i += 256 * 4)
        *(float4*)&sW[i] = *(const float4*)&Wfc[i];
    int nbase = blockIdx.x * 64;
    for (int i = tid * 4; i < 2048; i += 1024) {
        int n = nbase + (i >> 5);
        float4 v = make_float4(0.f, 0.f, 0.f, 0.f);
        if (n < NNODE) v = *(const float4*)&hin[n * 32 + (i & 31)];
        *(float4*)&sh[i] = v;
    }
    __syncthreads();
    int nl = tid >> 2, hh = tid & 3;
    int n = nbase + nl;
    float acc[32];
#pragma unroll
    for (int d = 0; d < 32; d++) acc[d] = 0.f;
#pragma unroll 8
    for (int k = 0; k < 32; k++) {
        float hk = sh[nl * 32 + k];
#pragma unroll
        for (int d = 0; d < 32; d++)
            acc[d] = fmaf(hk, sW[k * 128 + hh * 32 + d], acc[d]);
    }
    if (n < NNODE) {
        float e_l = 0.f, e_r = 0.f;
#pragma unroll
        for (int d = 0; d < 32; d++) {
            e_l = fmaf(acc[d], attn_l[hh * 32 + d], e_l);
            e_r = fmaf(acc[d], attn_r[hh * 32 + d], e_r);
        }
        el[n * 4 + hh] = e_l;
        er[n * 4 + hh] = e_r;
#pragma unroll
        for (int d = 0; d < 32; d += 4)
            *(float4*)&feat[n * 128 + hh * 32 + d] =
                make_float4(acc[d], acc[d + 1], acc[d + 2], acc[d + 3]);
    }
}

// ---------------- CSR build: histogram, scan, scatter ----------------
__global__ __launch_bounds__(256) void k_hist(const int* __restrict__ dst, int* __restrict__ cnt) {
    int i = blockIdx.x * 256 + threadIdx.x;
    int stride = gridDim.x * 256;
    for (int e = i; e < NEDGE; e += stride)
        atomicAdd(&cnt[dst[e]], 1);
}

__global__ __launch_bounds__(256) void k_scan1(const int* __restrict__ cnt,
                                               int* __restrict__ offtmp,
                                               int* __restrict__ blksum) {
    __shared__ int s[256];
    int t = threadIdx.x;
    int base = blockIdx.x * 1024 + t * 4;
    int v[4];
#pragma unroll
    for (int i = 0; i < 4; i++) {
        int n = base + i;
        v[i] = (n < NNODE) ? cnt[n] : 0;
    }
    int sum = v[0] + v[1] + v[2] + v[3];
    s[t] = sum;
    __syncthreads();
    for (int d = 1; d < 256; d <<= 1) {
        int x = (t >= d) ? s[t - d] : 0;
        __syncthreads();
        s[t] += x;
        __syncthreads();
    }
    int excl = s[t] - sum;
#pragma unroll
    for (int i = 0; i < 4; i++) {
        int n = base + i;
        if (n < NNODE) { offtmp[n] = excl; excl += v[i]; }
    }
    if (t == 255) blksum[blockIdx.x] = s[255];
}

__global__ __launch_bounds__(128) void k_scan2(int* __restrict__ blksum) {
    __shared__ int s[128];
    int t = threadIdx.x;
    int v = (t < NBLK_SCAN) ? blksum[t] : 0;
    s[t] = v;
    __syncthreads();
    for (int d = 1; d < 128; d <<= 1) {
        int x = (t >= d) ? s[t - d] : 0;
        __syncthreads();
        s[t] += x;
        __syncthreads();
    }
    if (t < NBLK_SCAN) blksum[t] = s[t] - v;   // exclusive
}

__global__ __launch_bounds__(256) void k_scan3(const int* __restrict__ offtmp,
                                               const int* __restrict__ blksum,
                                               int* __restrict__ off, int* __restrict__ cur) {
    int n = blockIdx.x * 256 + threadIdx.x;
    if (n < NNODE) {
        int o = offtmp[n] + blksum[n >> 10];
        off[n] = o;
        cur[n] = o;
    }
    if (n == 0) off[NNODE] = NEDGE;
}

__global__ __launch_bounds__(256) void k_scatter(const int* __restrict__ src,
                                                 const int* __restrict__ dst,
                                                 int* __restrict__ cur,
                                                 int* __restrict__ ssrc) {
    int i = blockIdx.x * 256 + threadIdx.x;
    int stride = gridDim.x * 256;
    for (int e = i; e < NEDGE; e += stride) {
        int d = dst[e];
        int pos = atomicAdd(&cur[d], 1);
        ssrc[pos] = src[e];
    }
}

// ---------------- K2': per-node gather + softmax + out-proj + ELU + residual ----------------
__global__ __launch_bounds__(256) void k_gather(
        const int* __restrict__ off, const int* __restrict__ ssrc,
        const float* __restrict__ el, const float* __restrict__ er,
        const float* __restrict__ feat, const float* __restrict__ bias_gat,
        const float* __restrict__ Wout, const float* __restrict__ b_out,
        const float* __restrict__ hin, float* __restrict__ out) {
    __shared__ float sW[128 * 32];     // 16 KB
    __shared__ float sv[2][128];
    __shared__ float sacc[2][4][32];
    int tid = threadIdx.x;
    for (int i = tid * 4; i < 4096; i += 1024)
        *(float4*)&sW[i] = *(const float4*)&Wout[i];
    int nl = tid >> 7;                 // node slot 0/1
    int c  = tid & 127;                // column 0..127
    int hh = c >> 5;                   // head
    int n = blockIdx.x * 2 + nl;
    float acc = 0.f, den = 0.f;
    int beg = 0, end = 0;
    float erv = 0.f;
    if (n < NNODE) {
        beg = off[n];
        end = off[n + 1];
        erv = er[n * 4 + hh];
    }
    for (int k = beg; k < end; k++) {
        int s = ssrc[k];
        float sc = el[s * 4 + hh] + erv;
        sc = sc > 0.f ? sc : 0.2f * sc;
        float ex = __expf(sc);
        acc = fmaf(ex, feat[s * 128 + c], acc);
        den += ex;
    }
    sv[nl][c] = acc / fmaxf(den, 1e-9f) + bias_gat[c];
    __syncthreads();
    // out projection: 4 partial groups of 32 per node column
    int g = c >> 5, j = c & 31;
    float p = 0.f;
    const float* vv = sv[nl];
#pragma unroll 8
    for (int cc = g * 32; cc < g * 32 + 32; cc++)
        p = fmaf(vv[cc], sW[cc * 32 + j], p);
    sacc[nl][g][j] = p;
    __syncthreads();
    if (g == 0 && n < NNODE) {
        float a = sacc[nl][0][j] + sacc[nl][1][j] + sacc[nl][2][j] + sacc[nl][3][j] + b_out[j];
        a = a > 0.f ? a : expm1f(a);
        out[n * 32 + j] = hin[n * 32 + j] + a;
    }
}

extern "C" void kernel_launch(void* const* d_in, const int* in_sizes, int n_in,
                              void* d_out, int out_size, void* d_ws, size_t ws_size,
                              hipStream_t stream) {
    const float* hin      = (const float*)d_in[0];
    const int*   src      = (const int*)d_in[1];
    const int*   dst      = (const int*)d_in[2];
    const float* Wfc      = (const float*)d_in[3];
    const float* attn_l   = (const float*)d_in[4];
    const float* attn_r   = (const float*)d_in[5];
    const float* bias_gat = (const float*)d_in[6];
    const float* Wout     = (const float*)d_in[7];
    const float* b_out    = (const float*)d_in[8];
    float* out = (float*)d_out;

    char* ws = (char*)d_ws;
    size_t o = 0;
    float* feat   = (float*)(ws + o); o += (size_t)NNODE * 128 * 4;
    float* el     = (float*)(ws + o); o += (size_t)NNODE * 4 * 4;
    float* er     = (float*)(ws + o); o += (size_t)NNODE * 4 * 4;
    int*   cnt    = (int*)(ws + o);   o += (size_t)NNODE * 4;
    int*   offtmp = (int*)(ws + o);   o += (size_t)NNODE * 4;
    int*   offa   = (int*)(ws + o);   o += (size_t)(NNODE + 1) * 4;
    int*   cur    = (int*)(ws + o);   o += (size_t)NNODE * 4;
    int*   blksum = (int*)(ws + o);   o += (size_t)NBLK_SCAN * 4;
    int*   ssrc   = (int*)(ws + o);   o += (size_t)NEDGE * 4;

    hipMemsetAsync(cnt, 0, (size_t)NNODE * 4, stream);

    k_proj<<<(NNODE + 63) / 64, 256, 0, stream>>>(hin, Wfc, attn_l, attn_r, feat, el, er);
    k_hist<<<2048, 256, 0, stream>>>(dst, cnt);
    k_scan1<<<NBLK_SCAN, 256, 0, stream>>>(cnt, offtmp, blksum);
    k_scan2<<<1, 128, 0, stream>>>(blksum);
    k_scan3<<<(NNODE + 255) / 256, 256, 0, stream>>>(offtmp, blksum, offa, cur);
    k_scatter<<<2048, 256, 0, stream>>>(src, dst, cur, ssrc);
    k_gather<<<(NNODE + 1) / 2, 256, 0, stream>>>(offa, ssrc, el, er, feat, bias_gat,
                                                  Wout, b_out, hin, out);
}

// Round 3
// 382.775 us; speedup vs baseline: 2.3639x; 1.5745x over previous
//
#include <hip/hip_runtime.h>

#define NNODE 100000
#define NEDGE 1600000
#define NBLK_SCAN 98   // ceil(100000/1024)

// ---------------- K1: feat = h @ W_fc, plus el/er ----------------
__global__ __launch_bounds__(256) void k_proj(
        const float* __restrict__ hin, const float* __restrict__ Wfc,
        const float* __restrict__ attn_l, const float* __restrict__ attn_r,
        float* __restrict__ feat, float* __restrict__ el, float* __restrict__ er) {
    __shared__ float sW[32 * 128];   // 16 KB
    __shared__ float sh[64 * 32];    // 8 KB
    int tid = threadIdx.x;
    for (int i = tid * 4; i < 4096; i += 256 * 4)
        *(float4*)&sW[i] = *(const float4*)&Wfc[i];
    int nbase = blockIdx.x * 64;
    for (int i = tid * 4; i < 2048; i += 1024) {
        int n = nbase + (i >> 5);
        float4 v = make_float4(0.f, 0.f, 0.f, 0.f);
        if (n < NNODE) v = *(const float4*)&hin[n * 32 + (i & 31)];
        *(float4*)&sh[i] = v;
    }
    __syncthreads();
    int nl = tid >> 2, hh = tid & 3;
    int n = nbase + nl;
    float acc[32];
#pragma unroll
    for (int d = 0; d < 32; d++) acc[d] = 0.f;
#pragma unroll 8
    for (int k = 0; k < 32; k++) {
        float hk = sh[nl * 32 + k];
#pragma unroll
        for (int d = 0; d < 32; d++)
            acc[d] = fmaf(hk, sW[k * 128 + hh * 32 + d], acc[d]);
    }
    if (n < NNODE) {
        float e_l = 0.f, e_r = 0.f;
#pragma unroll
        for (int d = 0; d < 32; d++) {
            e_l = fmaf(acc[d], attn_l[hh * 32 + d], e_l);
            e_r = fmaf(acc[d], attn_r[hh * 32 + d], e_r);
        }
        el[n * 4 + hh] = e_l;
        er[n * 4 + hh] = e_r;
#pragma unroll
        for (int d = 0; d < 32; d += 4)
            *(float4*)&feat[n * 128 + hh * 32 + d] =
                make_float4(acc[d], acc[d + 1], acc[d + 2], acc[d + 3]);
    }
}

// ---------------- CSR build: histogram, scan, scatter ----------------
__global__ __launch_bounds__(256) void k_hist(const int* __restrict__ dst, int* __restrict__ cnt) {
    int i = blockIdx.x * 256 + threadIdx.x;
    int stride = gridDim.x * 256;
    for (int e = i; e < NEDGE; e += stride)
        atomicAdd(&cnt[dst[e]], 1);
}

__global__ __launch_bounds__(256) void k_scan1(const int* __restrict__ cnt,
                                               int* __restrict__ offtmp,
                                               int* __restrict__ blksum) {
    __shared__ int s[256];
    int t = threadIdx.x;
    int base = blockIdx.x * 1024 + t * 4;
    int v[4];
#pragma unroll
    for (int i = 0; i < 4; i++) {
        int n = base + i;
        v[i] = (n < NNODE) ? cnt[n] : 0;
    }
    int sum = v[0] + v[1] + v[2] + v[3];
    s[t] = sum;
    __syncthreads();
    for (int d = 1; d < 256; d <<= 1) {
        int x = (t >= d) ? s[t - d] : 0;
        __syncthreads();
        s[t] += x;
        __syncthreads();
    }
    int excl = s[t] - sum;
#pragma unroll
    for (int i = 0; i < 4; i++) {
        int n = base + i;
        if (n < NNODE) { offtmp[n] = excl; excl += v[i]; }
    }
    if (t == 255) blksum[blockIdx.x] = s[255];
}

__global__ __launch_bounds__(128) void k_scan2(int* __restrict__ blksum) {
    __shared__ int s[128];
    int t = threadIdx.x;
    int v = (t < NBLK_SCAN) ? blksum[t] : 0;
    s[t] = v;
    __syncthreads();
    for (int d = 1; d < 128; d <<= 1) {
        int x = (t >= d) ? s[t - d] : 0;
        __syncthreads();
        s[t] += x;
        __syncthreads();
    }
    if (t < NBLK_SCAN) blksum[t] = s[t] - v;   // exclusive
}

__global__ __launch_bounds__(256) void k_scan3(const int* __restrict__ offtmp,
                                               const int* __restrict__ blksum,
                                               int* __restrict__ off, int* __restrict__ cur) {
    int n = blockIdx.x * 256 + threadIdx.x;
    if (n < NNODE) {
        int o = offtmp[n] + blksum[n >> 10];
        off[n] = o;
        cur[n] = o;
    }
    if (n == 0) off[NNODE] = NEDGE;
}

__global__ __launch_bounds__(256) void k_scatter(const int* __restrict__ src,
                                                 const int* __restrict__ dst,
                                                 int* __restrict__ cur,
                                                 int* __restrict__ ssrc) {
    int i = blockIdx.x * 256 + threadIdx.x;
    int stride = gridDim.x * 256;
    for (int e = i; e < NEDGE; e += stride) {
        int d = dst[e];
        int pos = atomicAdd(&cur[d], 1);
        ssrc[pos] = src[e];
    }
}

// ---------------- K2': wave-per-node gather + softmax + out-proj + ELU + residual ----
// 4 nodes per 256-thread block, one wave (64 lanes) per node, 2 columns per lane.
#define NPB 4
__global__ __launch_bounds__(256) void k_gather(
        const int* __restrict__ off, const int* __restrict__ ssrc,
        const float* __restrict__ el, const float* __restrict__ er,
        const float* __restrict__ feat, const float* __restrict__ bias_gat,
        const float* __restrict__ Wout, const float* __restrict__ b_out,
        const float* __restrict__ hin, float* __restrict__ out) {
    __shared__ float sW[128 * 32];                 // 16 KB
    __shared__ float sv[NPB][128];                 // 2 KB
    __shared__ float sacc[NPB][2][32];             // 1 KB
    __shared__ int   sS[NPB][64];                  // 1 KB
    __shared__ __align__(16) float sE[NPB][64][4]; // 4 KB
    int tid = threadIdx.x;
    for (int i = tid * 4; i < 4096; i += 1024)
        *(float4*)&sW[i] = *(const float4*)&Wout[i];
    int w = tid >> 6;            // wave index = node slot
    int l = tid & 63;            // lane
    int n = blockIdx.x * NPB + w;   // grid is exact: 25000*4 = 100000
    int c0 = l * 2;              // columns c0, c0+1 (same head)
    int hh = l >> 4;             // head for this lane's column pair
    float2 acc = make_float2(0.f, 0.f);
    float den = 0.f;
    int beg = off[n], end = off[n + 1];
    float4 erv = *(const float4*)&er[n * 4];

    for (int base = beg; base < end; base += 64) {
        int cnt = end - base; if (cnt > 64) cnt = 64;
        // phase A: parallel edge-metadata load, all 4 heads' exp()
        if (l < cnt) {
            int s = ssrc[base + l];
            float4 ev = *(const float4*)&el[s * 4];
            float4 e4;
            e4.x = ev.x + erv.x; e4.x = e4.x > 0.f ? e4.x : 0.2f * e4.x; e4.x = __expf(e4.x);
            e4.y = ev.y + erv.y; e4.y = e4.y > 0.f ? e4.y : 0.2f * e4.y; e4.y = __expf(e4.y);
            e4.z = ev.z + erv.z; e4.z = e4.z > 0.f ? e4.z : 0.2f * e4.z; e4.z = __expf(e4.z);
            e4.w = ev.w + erv.w; e4.w = e4.w > 0.f ? e4.w : 0.2f * e4.w; e4.w = __expf(e4.w);
            sS[w][l] = s;
            *(float4*)&sE[w][l][0] = e4;
        }
        __builtin_amdgcn_wave_barrier();   // wave-local LDS RAW: keep order
        // phase B: column gather, 4 edges in flight
        int e = 0;
        for (; e + 4 <= cnt; e += 4) {
            int s0 = sS[w][e], s1 = sS[w][e + 1], s2 = sS[w][e + 2], s3 = sS[w][e + 3];
            float x0 = sE[w][e][hh], x1 = sE[w][e + 1][hh];
            float x2 = sE[w][e + 2][hh], x3 = sE[w][e + 3][hh];
            float2 f0 = *(const float2*)&feat[(size_t)s0 * 128 + c0];
            float2 f1 = *(const float2*)&feat[(size_t)s1 * 128 + c0];
            float2 f2 = *(const float2*)&feat[(size_t)s2 * 128 + c0];
            float2 f3 = *(const float2*)&feat[(size_t)s3 * 128 + c0];
            den += (x0 + x1) + (x2 + x3);
            acc.x = fmaf(x0, f0.x, acc.x); acc.y = fmaf(x0, f0.y, acc.y);
            acc.x = fmaf(x1, f1.x, acc.x); acc.y = fmaf(x1, f1.y, acc.y);
            acc.x = fmaf(x2, f2.x, acc.x); acc.y = fmaf(x2, f2.y, acc.y);
            acc.x = fmaf(x3, f3.x, acc.x); acc.y = fmaf(x3, f3.y, acc.y);
        }
        for (; e < cnt; e++) {
            int s0 = sS[w][e];
            float x0 = sE[w][e][hh];
            float2 f0 = *(const float2*)&feat[(size_t)s0 * 128 + c0];
            den += x0;
            acc.x = fmaf(x0, f0.x, acc.x); acc.y = fmaf(x0, f0.y, acc.y);
        }
        __builtin_amdgcn_wave_barrier();   // don't overwrite LDS before reads done
    }
    float inv = 1.f / fmaxf(den, 1e-9f);
    float2 val;
    val.x = acc.x * inv + bias_gat[c0];
    val.y = acc.y * inv + bias_gat[c0 + 1];
    *(float2*)&sv[w][c0] = val;
    __syncthreads();
    // epilogue: out = h + ELU(sv @ Wout + b_out); thread = (w, g2, j)
    int j = tid & 31, g2 = (l >> 5);
    float p = 0.f;
    const float* vv = sv[w];
#pragma unroll 16
    for (int cc = g2 * 64; cc < g2 * 64 + 64; cc++)
        p = fmaf(vv[cc], sW[cc * 32 + j], p);
    sacc[w][g2][j] = p;
    __syncthreads();
    if (g2 == 0) {
        float a = sacc[w][0][j] + sacc[w][1][j] + b_out[j];
        a = a > 0.f ? a : expm1f(a);
        out[n * 32 + j] = hin[n * 32 + j] + a;
    }
}

extern "C" void kernel_launch(void* const* d_in, const int* in_sizes, int n_in,
                              void* d_out, int out_size, void* d_ws, size_t ws_size,
                              hipStream_t stream) {
    const float* hin      = (const float*)d_in[0];
    const int*   src      = (const int*)d_in[1];
    const int*   dst      = (const int*)d_in[2];
    const float* Wfc      = (const float*)d_in[3];
    const float* attn_l   = (const float*)d_in[4];
    const float* attn_r   = (const float*)d_in[5];
    const float* bias_gat = (const float*)d_in[6];
    const float* Wout     = (const float*)d_in[7];
    const float* b_out    = (const float*)d_in[8];
    float* out = (float*)d_out;

    char* ws = (char*)d_ws;
    size_t o = 0;
    float* feat   = (float*)(ws + o); o += (size_t)NNODE * 128 * 4;
    float* el     = (float*)(ws + o); o += (size_t)NNODE * 4 * 4;
    float* er     = (float*)(ws + o); o += (size_t)NNODE * 4 * 4;
    int*   cnt    = (int*)(ws + o);   o += (size_t)NNODE * 4;
    int*   offtmp = (int*)(ws + o);   o += (size_t)NNODE * 4;
    int*   offa   = (int*)(ws + o);   o += (size_t)(NNODE + 1) * 4;
    int*   cur    = (int*)(ws + o);   o += (size_t)NNODE * 4;
    int*   blksum = (int*)(ws + o);   o += (size_t)NBLK_SCAN * 4;
    int*   ssrc   = (int*)(ws + o);   o += (size_t)NEDGE * 4;

    hipMemsetAsync(cnt, 0, (size_t)NNODE * 4, stream);

    k_proj<<<(NNODE + 63) / 64, 256, 0, stream>>>(hin, Wfc, attn_l, attn_r, feat, el, er);
    k_hist<<<2048, 256, 0, stream>>>(dst, cnt);
    k_scan1<<<NBLK_SCAN, 256, 0, stream>>>(cnt, offtmp, blksum);
    k_scan2<<<1, 128, 0, stream>>>(blksum);
    k_scan3<<<(NNODE + 255) / 256, 256, 0, stream>>>(offtmp, blksum, offa, cur);
    k_scatter<<<2048, 256, 0, stream>>>(src, dst, cur, ssrc);
    k_gather<<<NNODE / NPB, 256, 0, stream>>>(offa, ssrc, el, er, feat, bias_gat,
                                              Wout, b_out, hin, out);
}

// Round 4
// 343.963 us; speedup vs baseline: 2.6307x; 1.1128x over previous
//
#include <hip/hip_runtime.h>
#include <hip/hip_bf16.h>

#define NNODE 100000
#define NEDGE 1600000
#define NBLK_SCAN 98   // ceil(100000/1024)

static __device__ __forceinline__ uint32_t pack_bf16(float a, float b) {
    __hip_bfloat162 t = __float22bfloat162_rn(make_float2(a, b));
    return *(uint32_t*)&t;
}

// ---------------- K1: feat = h @ W_fc (bf16 out), plus el/er (f32) ----------------
__global__ __launch_bounds__(256) void k_proj(
        const float* __restrict__ hin, const float* __restrict__ Wfc,
        const float* __restrict__ attn_l, const float* __restrict__ attn_r,
        uint32_t* __restrict__ feat, float* __restrict__ el, float* __restrict__ er) {
    __shared__ float sW[32 * 128];   // 16 KB
    __shared__ float sh[64 * 32];    // 8 KB
    int tid = threadIdx.x;
    for (int i = tid * 4; i < 4096; i += 256 * 4)
        *(float4*)&sW[i] = *(const float4*)&Wfc[i];
    int nbase = blockIdx.x * 64;
    for (int i = tid * 4; i < 2048; i += 1024) {
        int n = nbase + (i >> 5);
        float4 v = make_float4(0.f, 0.f, 0.f, 0.f);
        if (n < NNODE) v = *(const float4*)&hin[n * 32 + (i & 31)];
        *(float4*)&sh[i] = v;
    }
    __syncthreads();
    int nl = tid >> 2, hh = tid & 3;
    int n = nbase + nl;
    float acc[32];
#pragma unroll
    for (int d = 0; d < 32; d++) acc[d] = 0.f;
#pragma unroll 8
    for (int k = 0; k < 32; k++) {
        float hk = sh[nl * 32 + k];
#pragma unroll
        for (int d = 0; d < 32; d++)
            acc[d] = fmaf(hk, sW[k * 128 + hh * 32 + d], acc[d]);
    }
    if (n < NNODE) {
        float e_l = 0.f, e_r = 0.f;
#pragma unroll
        for (int d = 0; d < 32; d++) {
            e_l = fmaf(acc[d], attn_l[hh * 32 + d], e_l);
            e_r = fmaf(acc[d], attn_r[hh * 32 + d], e_r);
        }
        el[n * 4 + hh] = e_l;
        er[n * 4 + hh] = e_r;
        // pack 32 cols -> 16 uints -> 4x uint4 stores
        uint4 u[4];
#pragma unroll
        for (int q = 0; q < 4; q++) {
            u[q].x = pack_bf16(acc[q * 8 + 0], acc[q * 8 + 1]);
            u[q].y = pack_bf16(acc[q * 8 + 2], acc[q * 8 + 3]);
            u[q].z = pack_bf16(acc[q * 8 + 4], acc[q * 8 + 5]);
            u[q].w = pack_bf16(acc[q * 8 + 6], acc[q * 8 + 7]);
        }
#pragma unroll
        for (int q = 0; q < 4; q++)
            *(uint4*)&feat[(size_t)n * 64 + hh * 16 + q * 4] = u[q];
    }
}

// ---------------- CSR build: histogram, scan, scatter ----------------
__global__ __launch_bounds__(256) void k_hist(const int* __restrict__ dst, int* __restrict__ cnt) {
    int i = blockIdx.x * 256 + threadIdx.x;
    int stride = gridDim.x * 256;
    const int4* d4 = (const int4*)dst;
    for (int e = i; e < NEDGE / 4; e += stride) {
        int4 d = d4[e];
        atomicAdd(&cnt[d.x], 1);
        atomicAdd(&cnt[d.y], 1);
        atomicAdd(&cnt[d.z], 1);
        atomicAdd(&cnt[d.w], 1);
    }
}

__global__ __launch_bounds__(256) void k_scan1(const int* __restrict__ cnt,
                                               int* __restrict__ offtmp,
                                               int* __restrict__ blksum) {
    __shared__ int s[256];
    int t = threadIdx.x;
    int base = blockIdx.x * 1024 + t * 4;
    int v[4];
#pragma unroll
    for (int i = 0; i < 4; i++) {
        int n = base + i;
        v[i] = (n < NNODE) ? cnt[n] : 0;
    }
    int sum = v[0] + v[1] + v[2] + v[3];
    s[t] = sum;
    __syncthreads();
    for (int d = 1; d < 256; d <<= 1) {
        int x = (t >= d) ? s[t - d] : 0;
        __syncthreads();
        s[t] += x;
        __syncthreads();
    }
    int excl = s[t] - sum;
#pragma unroll
    for (int i = 0; i < 4; i++) {
        int n = base + i;
        if (n < NNODE) { offtmp[n] = excl; excl += v[i]; }
    }
    if (t == 255) blksum[blockIdx.x] = s[255];
}

__global__ __launch_bounds__(128) void k_scan2(int* __restrict__ blksum) {
    __shared__ int s[128];
    int t = threadIdx.x;
    int v = (t < NBLK_SCAN) ? blksum[t] : 0;
    s[t] = v;
    __syncthreads();
    for (int d = 1; d < 128; d <<= 1) {
        int x = (t >= d) ? s[t - d] : 0;
        __syncthreads();
        s[t] += x;
        __syncthreads();
    }
    if (t < NBLK_SCAN) blksum[t] = s[t] - v;   // exclusive
}

__global__ __launch_bounds__(256) void k_scan3(const int* __restrict__ offtmp,
                                               const int* __restrict__ blksum,
                                               int* __restrict__ off, int* __restrict__ cur) {
    int n = blockIdx.x * 256 + threadIdx.x;
    if (n < NNODE) {
        int o = offtmp[n] + blksum[n >> 10];
        off[n] = o;
        cur[n] = o;
    }
    if (n == 0) off[NNODE] = NEDGE;
}

__global__ __launch_bounds__(256) void k_scatter(const int* __restrict__ src,
                                                 const int* __restrict__ dst,
                                                 int* __restrict__ cur,
                                                 int* __restrict__ ssrc) {
    int i = blockIdx.x * 256 + threadIdx.x;
    int stride = gridDim.x * 256;
    const int4* s4 = (const int4*)src;
    const int4* d4 = (const int4*)dst;
    for (int e = i; e < NEDGE / 4; e += stride) {
        int4 s = s4[e];
        int4 d = d4[e];
        ssrc[atomicAdd(&cur[d.x], 1)] = s.x;
        ssrc[atomicAdd(&cur[d.y], 1)] = s.y;
        ssrc[atomicAdd(&cur[d.z], 1)] = s.z;
        ssrc[atomicAdd(&cur[d.w], 1)] = s.w;
    }
}

// ---------------- K2': wave-per-node gather + softmax + out-proj + ELU + residual ----
// 4 nodes per 256-thread block, one wave (64 lanes) per node, 2 columns per lane.
#define NPB 4
__global__ __launch_bounds__(256) void k_gather(
        const int* __restrict__ off, const int* __restrict__ ssrc,
        const float* __restrict__ el, const float* __restrict__ er,
        const uint32_t* __restrict__ feat, const float* __restrict__ bias_gat,
        const float* __restrict__ Wout, const float* __restrict__ b_out,
        const float* __restrict__ hin, float* __restrict__ out) {
    __shared__ float sW[128 * 32];                 // 16 KB
    __shared__ float sv[NPB][128];                 // 2 KB
    __shared__ float sacc[NPB][2][32];             // 1 KB
    __shared__ int   sS[NPB][64];                  // 1 KB
    __shared__ __align__(16) float sE[NPB][64][4]; // 4 KB
    int tid = threadIdx.x;
    for (int i = tid * 4; i < 4096; i += 1024)
        *(float4*)&sW[i] = *(const float4*)&Wout[i];
    int w = tid >> 6;            // wave index = node slot
    int l = tid & 63;            // lane
    int n = blockIdx.x * NPB + w;   // grid exact: 25000*4 = 100000
    int c0 = l * 2;              // columns c0, c0+1 (same head)
    int hh = l >> 4;             // head for this lane's column pair
    float2 acc = make_float2(0.f, 0.f);
    float den = 0.f;
    int beg = off[n], end = off[n + 1];
    float4 erv = *(const float4*)&er[n * 4];

    for (int base = beg; base < end; base += 64) {
        int cnt = end - base; if (cnt > 64) cnt = 64;
        // phase A: parallel edge-metadata load, all 4 heads' exp()
        if (l < cnt) {
            int s = ssrc[base + l];
            float4 ev = *(const float4*)&el[s * 4];
            float4 e4;
            e4.x = ev.x + erv.x; e4.x = e4.x > 0.f ? e4.x : 0.2f * e4.x; e4.x = __expf(e4.x);
            e4.y = ev.y + erv.y; e4.y = e4.y > 0.f ? e4.y : 0.2f * e4.y; e4.y = __expf(e4.y);
            e4.z = ev.z + erv.z; e4.z = e4.z > 0.f ? e4.z : 0.2f * e4.z; e4.z = __expf(e4.z);
            e4.w = ev.w + erv.w; e4.w = e4.w > 0.f ? e4.w : 0.2f * e4.w; e4.w = __expf(e4.w);
            sS[w][l] = s;
            *(float4*)&sE[w][l][0] = e4;
        }
        __builtin_amdgcn_wave_barrier();   // wave-local LDS RAW: keep order
        // phase B: column gather, 4 edges in flight, bf16 rows (1 dword/lane/edge)
        int e = 0;
        for (; e + 4 <= cnt; e += 4) {
            int s0 = sS[w][e], s1 = sS[w][e + 1], s2 = sS[w][e + 2], s3 = sS[w][e + 3];
            float x0 = sE[w][e][hh], x1 = sE[w][e + 1][hh];
            float x2 = sE[w][e + 2][hh], x3 = sE[w][e + 3][hh];
            uint32_t u0 = feat[(size_t)s0 * 64 + l];
            uint32_t u1 = feat[(size_t)s1 * 64 + l];
            uint32_t u2 = feat[(size_t)s2 * 64 + l];
            uint32_t u3 = feat[(size_t)s3 * 64 + l];
            den += (x0 + x1) + (x2 + x3);
            acc.x = fmaf(x0, __uint_as_float(u0 << 16), acc.x);
            acc.y = fmaf(x0, __uint_as_float(u0 & 0xffff0000u), acc.y);
            acc.x = fmaf(x1, __uint_as_float(u1 << 16), acc.x);
            acc.y = fmaf(x1, __uint_as_float(u1 & 0xffff0000u), acc.y);
            acc.x = fmaf(x2, __uint_as_float(u2 << 16), acc.x);
            acc.y = fmaf(x2, __uint_as_float(u2 & 0xffff0000u), acc.y);
            acc.x = fmaf(x3, __uint_as_float(u3 << 16), acc.x);
            acc.y = fmaf(x3, __uint_as_float(u3 & 0xffff0000u), acc.y);
        }
        for (; e < cnt; e++) {
            int s0 = sS[w][e];
            float x0 = sE[w][e][hh];
            uint32_t u0 = feat[(size_t)s0 * 64 + l];
            den += x0;
            acc.x = fmaf(x0, __uint_as_float(u0 << 16), acc.x);
            acc.y = fmaf(x0, __uint_as_float(u0 & 0xffff0000u), acc.y);
        }
        __builtin_amdgcn_wave_barrier();   // don't overwrite LDS before reads done
    }
    float inv = 1.f / fmaxf(den, 1e-9f);
    float2 val;
    val.x = acc.x * inv + bias_gat[c0];
    val.y = acc.y * inv + bias_gat[c0 + 1];
    *(float2*)&sv[w][c0] = val;
    __syncthreads();
    // epilogue: out = h + ELU(sv @ Wout + b_out); thread = (w, g2, j)
    int j = tid & 31, g2 = (l >> 5);
    float p = 0.f;
    const float* vv = sv[w];
#pragma unroll 16
    for (int cc = g2 * 64; cc < g2 * 64 + 64; cc++)
        p = fmaf(vv[cc], sW[cc * 32 + j], p);
    sacc[w][g2][j] = p;
    __syncthreads();
    if (g2 == 0) {
        float a = sacc[w][0][j] + sacc[w][1][j] + b_out[j];
        a = a > 0.f ? a : expm1f(a);
        out[n * 32 + j] = hin[n * 32 + j] + a;
    }
}

extern "C" void kernel_launch(void* const* d_in, const int* in_sizes, int n_in,
                              void* d_out, int out_size, void* d_ws, size_t ws_size,
                              hipStream_t stream) {
    const float* hin      = (const float*)d_in[0];
    const int*   src      = (const int*)d_in[1];
    const int*   dst      = (const int*)d_in[2];
    const float* Wfc      = (const float*)d_in[3];
    const float* attn_l   = (const float*)d_in[4];
    const float* attn_r   = (const float*)d_in[5];
    const float* bias_gat = (const float*)d_in[6];
    const float* Wout     = (const float*)d_in[7];
    const float* b_out    = (const float*)d_in[8];
    float* out = (float*)d_out;

    char* ws = (char*)d_ws;
    size_t o = 0;
    uint32_t* feat = (uint32_t*)(ws + o); o += (size_t)NNODE * 64 * 4;  // bf16 x128
    float* el     = (float*)(ws + o); o += (size_t)NNODE * 4 * 4;
    float* er     = (float*)(ws + o); o += (size_t)NNODE * 4 * 4;
    int*   cnt    = (int*)(ws + o);   o += (size_t)NNODE * 4;
    int*   offtmp = (int*)(ws + o);   o += (size_t)NNODE * 4;
    int*   offa   = (int*)(ws + o);   o += (size_t)(NNODE + 1) * 4;
    int*   cur    = (int*)(ws + o);   o += (size_t)NNODE * 4;
    int*   blksum = (int*)(ws + o);   o += (size_t)NBLK_SCAN * 4;
    int*   ssrc   = (int*)(ws + o);   o += (size_t)NEDGE * 4;

    hipMemsetAsync(cnt, 0, (size_t)NNODE * 4, stream);

    k_proj<<<(NNODE + 63) / 64, 256, 0, stream>>>(hin, Wfc, attn_l, attn_r, feat, el, er);
    k_hist<<<1024, 256, 0, stream>>>(dst, cnt);
    k_scan1<<<NBLK_SCAN, 256, 0, stream>>>(cnt, offtmp, blksum);
    k_scan2<<<1, 128, 0, stream>>>(blksum);
    k_scan3<<<(NNODE + 255) / 256, 256, 0, stream>>>(offtmp, blksum, offa, cur);
    k_scatter<<<1024, 256, 0, stream>>>(src, dst, cur, ssrc);
    k_gather<<<NNODE / NPB, 256, 0, stream>>>(offa, ssrc, el, er, feat, bias_gat,
                                              Wout, b_out, hin, out);
}